// Round 6
// baseline (174.970 us; speedup 1.0000x reference)
//
#include <hip/hip_runtime.h>

// patches: [N=128, C=4, P=32, P, P] fp32 ; vol/out: [B=2, C=4, 128,128,128] fp32
// centers: [N,3] int32 ; lo = center-16 ; patch n -> batch b = n/64
// out = 0.5*vol + 0.5*scatter(patches), computed as a per-block cooperative
// GATHER through an LDS accumulator tile (no global atomics).
// Block footprint: fixed h, w in [w0,w0+8), full d axis (128).
//   phase 0: issue vol4 loads early (latency hidden under gather)
//   phase 1: wave0 ballot-filters the 64 patches vs the block footprint
//   phase 2: per surviving patch, block cooperatively loads ALIGNED float4s
//            of the patch rows (each patch line touched exactly once) and
//            ds_add_f32-accumulates into acc[c][w'][d] (misalignment lo2&3
//            absorbed by LDS addressing)
//   phase 3: out = 0.5*vol + 0.5*acc

constexpr int NPB = 64;                  // patches per batch
constexpr int CH4 = 128 * 128 * 32;      // vol channel stride in float4 (524288)
constexpr int PCH4 = 32 * 32 * 8;        // patch channel stride in float4 (8192)

__global__ __launch_bounds__(256) void patch_gather_kernel(
        const float4* __restrict__ patches4,
        const int*   __restrict__ centers,
        const float4* __restrict__ vol4,
        float4* __restrict__ out4) {
    __shared__ float s_acc[4 * 8 * 128];  // [c][w'][d] = 16 KB
    __shared__ int s_list[NPB];
    __shared__ int s_n;

    int blk = blockIdx.x;
    int b   = blk >> 11;                 // 2048 blocks per batch
    int blo = blk & 2047;
    int tid = threadIdx.x;

    int h  = blo >> 4;                   // block-uniform h
    int w0 = (blo << 3) & 127;           // block covers w0..w0+7

    // ---- phase 0: issue vol loads early --------------------------------
    int base4 = (((b * 4) * 128 + h) * 128 + (w0 + (tid >> 5))) * 32 + (tid & 31);
    float4 v0 = vol4[base4];
    float4 v1 = vol4[base4 + CH4];
    float4 v2 = vol4[base4 + 2 * CH4];
    float4 v3 = vol4[base4 + 3 * CH4];

    // ---- zero the LDS accumulator --------------------------------------
    float4* sa4 = (float4*)s_acc;
    #pragma unroll
    for (int j = 0; j < 4; ++j)
        sa4[tid + j * 256] = make_float4(0.f, 0.f, 0.f, 0.f);

    // ---- phase 1: filter (wave 0) --------------------------------------
    if (tid < 64) {
        int lo0 = centers[(b * NPB + tid) * 3 + 0] - 16;
        int lo1 = centers[(b * NPB + tid) * 3 + 1] - 16;
        int lo2 = centers[(b * NPB + tid) * 3 + 2] - 16;
        int wlo = max(lo1, w0), whi = min(lo1 + 31, w0 + 7);
        int nw = whi - wlo + 1;
        bool hit = ((unsigned)(h - lo0) < 32u) && (nw > 0);
        unsigned long long m = __ballot(hit);
        if (hit) {
            int pos = __popcll(m & ((1ull << tid) - 1ull));
            int hi = h - lo0;            // 0..31
            int wi0 = wlo - lo1;         // patch-w of first covered column
            int wOff = wlo - w0;         // block-w' of first covered column
            s_list[pos] = (tid << 24) | (hi << 19) | (lo2 << 12) |
                          (wi0 << 7) | (wOff << 4) | nw;
        }
        if (tid == 0) s_n = __popcll(m);
    }
    __syncthreads();

    // ---- phase 2: cooperative aligned gather into LDS ------------------
    int nh = s_n;
    const float4* pbase = patches4 + (size_t)b * NPB * 4 * PCH4;
    for (int i = 0; i < nh; ++i) {
        int e  = s_list[i];              // broadcast
        int nw = e & 15;
        if (tid < (nw << 5)) {           // 32 threads per covered w-column
            int k4   = tid & 7;          // patch float4 along k
            int c    = (tid >> 3) & 3;
            int woff = tid >> 5;
            int pn   = e >> 24;
            int hi   = (e >> 19) & 31;
            int lo2  = (e >> 12) & 127;
            int wi0  = (e >> 7) & 31;
            int wOff = (e >> 4) & 7;
            float4 pv = pbase[(size_t)(pn * 4 + c) * PCH4 +
                              (hi * 32 + wi0 + woff) * 8 + k4];
            float* a = &s_acc[(c * 8 + wOff + woff) * 128 + lo2 + (k4 << 2)];
            atomicAdd(a + 0, pv.x);      // ds_add_f32 (LDS atomic, no return)
            atomicAdd(a + 1, pv.y);
            atomicAdd(a + 2, pv.z);
            atomicAdd(a + 3, pv.w);
        }
    }
    __syncthreads();

    // ---- phase 3: epilogue ---------------------------------------------
    int l4 = (tid >> 5) * 32 + (tid & 31);   // [w'][d4] within a channel plane
    #pragma unroll
    for (int c = 0; c < 4; ++c) {
        float4 acc = sa4[c * 256 + l4];
        float4 v = (c == 0) ? v0 : (c == 1) ? v1 : (c == 2) ? v2 : v3;
        float4 o;
        o.x = (v.x + acc.x) * 0.5f;
        o.y = (v.y + acc.y) * 0.5f;
        o.z = (v.z + acc.z) * 0.5f;
        o.w = (v.w + acc.w) * 0.5f;
        out4[base4 + c * CH4] = o;
    }
}

extern "C" void kernel_launch(void* const* d_in, const int* in_sizes, int n_in,
                              void* d_out, int out_size, void* d_ws, size_t ws_size,
                              hipStream_t stream) {
    const float* patches = (const float*)d_in[0];
    const float* vol     = (const float*)d_in[1];
    const int*   centers = (const int*)d_in[2];
    float* out = (float*)d_out;

    patch_gather_kernel<<<4096, 256, 0, stream>>>(
        (const float4*)patches, centers, (const float4*)vol, (float4*)out);
}

// Round 9
// 59.120 us; speedup vs baseline: 2.9596x; 2.9596x over previous
//
#include <hip/hip_runtime.h>

// patches: [N=128, C=4, P=32, P, P] fp32 ; vol/out: [B=2, C=4, 128,128,128] fp32
// centers: [N,3] int32 ; lo = center-16 ; patch n -> batch b = n/64
// out = 0.5*vol + 0.5*scatter(patches), computed as a GATHER (no atomics).
// Per-block ballot-compacted candidate list (R5 structure, 53.6us) plus:
//  - vol4 loads issued FIRST (latency hidden under filter+gather)
//  - aligned float4 patch gather: the 4 needed elems span 2 aligned float4s,
//    combined by a wave-uniform shift (k0&3 is lane-invariant) -> coalesced
//  - s_list entry prefetch (LDS latency off the per-iteration chain)

constexpr int C = 4, H = 128, P = 32;
constexpr int NPB  = 64;               // patches per batch
constexpr int CH4  = H * H * H / 4;    // vol channel stride in float4 (524288)
constexpr int PCH4 = P * P * P / 4;    // patch channel stride in float4 (8192)

__global__ __launch_bounds__(256) void patch_gather_kernel(
        const float4* __restrict__ patches4,
        const int*   __restrict__ centers,
        const float4* __restrict__ vol4,
        float4* __restrict__ out4) {
    __shared__ int s_list[NPB];
    __shared__ int s_n;

    int blk = blockIdx.x;
    int b   = blk >> 11;               // 2048 blocks per batch
    int blo = blk & 2047;
    int tid = threadIdx.x;

    int h  = blo >> 4;                 // block-uniform h
    int w0 = (blo & 15) << 3;          // block covers w0..w0+7

    int d4 = tid & 31;                 // float4 index along d
    int w  = w0 + (tid >> 5);
    int d0 = d4 << 2;

    // ---- issue vol loads EARLY ----------------------------------------
    int base4 = (((b * C) * H + h) * H + w) * 32 + d4;
    float4 v0 = vol4[base4];
    float4 v1 = vol4[base4 + CH4];
    float4 v2 = vol4[base4 + 2 * CH4];
    float4 v3 = vol4[base4 + 3 * CH4];

    // ---- wave0: ballot-compacted per-block candidate list --------------
    if (tid < 64) {
        int lo0 = centers[(b * NPB + tid) * 3 + 0] - 16;
        int lo1 = centers[(b * NPB + tid) * 3 + 1] - 16;
        int lo2 = centers[(b * NPB + tid) * 3 + 2] - 16;
        bool hit = ((unsigned)(h - lo0) < 32u) &&
                   ((unsigned)(w0 - lo1 + 7) < 39u);   // w-range intersect
        unsigned long long m = __ballot(hit);
        if (hit) {
            int pos = __popcll(m & ((1ull << tid) - 1ull));
            s_list[pos] = (tid << 21) | ((h - lo0) << 14) | (lo1 << 7) | lo2;
        }
        if (tid == 0) s_n = __popcll(m);
    }
    __syncthreads();

    int nh = s_n;
    float4 acc[4] = {};                // [c], components = 4 consecutive d
    const float4* pbat = patches4 + (size_t)b * NPB * C * PCH4;

    int enext = (nh > 0) ? s_list[0] : 0;
    for (int i = 0; i < nh; ++i) {
        int e = enext;
        enext = s_list[(i + 1 < nh) ? i + 1 : i];      // prefetch next
        int pn  = e >> 21;
        int hi  = (e >> 14) & 31;
        int lo1 = (e >> 7) & 127;
        int lo2 = e & 127;
        int wi  = w - lo1;
        int k0  = d0 - lo2;            // patch-k of this thread's first elem
        bool hit = ((unsigned)wi < 32u) && (k0 > -4) && (k0 < 32);

        float4 z = make_float4(0.f, 0.f, 0.f, 0.f);
        float4 a0 = z, a1 = z, a2 = z, a3 = z, b0 = z, b1 = z, b2 = z, b3 = z;
        if (hit) {
            int q = (k0 + 4) >> 2;     // 0..8
            int ka = q - 1, kb = q;    // aligned float4 window
            const float4* pr = pbat + (size_t)pn * C * PCH4 + (hi * 32 + wi) * 8;
            if ((unsigned)ka < 8u) {
                a0 = pr[ka];           a1 = pr[PCH4 + ka];
                a2 = pr[2 * PCH4 + ka]; a3 = pr[3 * PCH4 + ka];
            }
            if ((unsigned)kb < 8u) {
                b0 = pr[kb];           b1 = pr[PCH4 + kb];
                b2 = pr[2 * PCH4 + kb]; b3 = pr[3 * PCH4 + kb];
            }
        }
        // k0 & 3 == (-lo2) & 3 : identical for every lane (d0 % 4 == 0)
        int shift = __builtin_amdgcn_readfirstlane(k0 & 3);

#define SH0(c, A, B) acc[c].x += A.x; acc[c].y += A.y; acc[c].z += A.z; acc[c].w += A.w;
#define SH1(c, A, B) acc[c].x += A.y; acc[c].y += A.z; acc[c].z += A.w; acc[c].w += B.x;
#define SH2(c, A, B) acc[c].x += A.z; acc[c].y += A.w; acc[c].z += B.x; acc[c].w += B.y;
#define SH3(c, A, B) acc[c].x += A.w; acc[c].y += B.x; acc[c].z += B.y; acc[c].w += B.z;
        switch (shift) {
        case 0: SH0(0, a0, b0) SH0(1, a1, b1) SH0(2, a2, b2) SH0(3, a3, b3) break;
        case 1: SH1(0, a0, b0) SH1(1, a1, b1) SH1(2, a2, b2) SH1(3, a3, b3) break;
        case 2: SH2(0, a0, b0) SH2(1, a1, b1) SH2(2, a2, b2) SH2(3, a3, b3) break;
        default: SH3(0, a0, b0) SH3(1, a1, b1) SH3(2, a2, b2) SH3(3, a3, b3) break;
        }
    }

    // ---- epilogue: out = 0.5*(vol + acc) -------------------------------
    float4 o;
    o.x = (v0.x + acc[0].x) * 0.5f; o.y = (v0.y + acc[0].y) * 0.5f;
    o.z = (v0.z + acc[0].z) * 0.5f; o.w = (v0.w + acc[0].w) * 0.5f;
    out4[base4] = o;
    o.x = (v1.x + acc[1].x) * 0.5f; o.y = (v1.y + acc[1].y) * 0.5f;
    o.z = (v1.z + acc[1].z) * 0.5f; o.w = (v1.w + acc[1].w) * 0.5f;
    out4[base4 + CH4] = o;
    o.x = (v2.x + acc[2].x) * 0.5f; o.y = (v2.y + acc[2].y) * 0.5f;
    o.z = (v2.z + acc[2].z) * 0.5f; o.w = (v2.w + acc[2].w) * 0.5f;
    out4[base4 + 2 * CH4] = o;
    o.x = (v3.x + acc[3].x) * 0.5f; o.y = (v3.y + acc[3].y) * 0.5f;
    o.z = (v3.z + acc[3].z) * 0.5f; o.w = (v3.w + acc[3].w) * 0.5f;
    out4[base4 + 3 * CH4] = o;
}

extern "C" void kernel_launch(void* const* d_in, const int* in_sizes, int n_in,
                              void* d_out, int out_size, void* d_ws, size_t ws_size,
                              hipStream_t stream) {
    const float* patches = (const float*)d_in[0];
    const float* vol     = (const float*)d_in[1];
    const int*   centers = (const int*)d_in[2];
    float* out = (float*)d_out;

    patch_gather_kernel<<<4096, 256, 0, stream>>>(
        (const float4*)patches, centers, (const float4*)vol, (float4*)out);
}